// Round 13
// baseline (644.017 us; speedup 1.0000x reference)
//
#include <hip/hip_runtime.h>
#include <math.h>

#define LSEQ 2304
#define DM 128
#define DI 256
#define DS 16
#define RK 8
#define NCH 576     // 4-row chunks
#define CLEN 4
#define NG 24       // carry groups
#define GS 24       // chunks per group (NG*GS == NCH)
#define NSI (DI*DS) // 4096 state indices
#define EPSF 1e-5f

__device__ __forceinline__ float silu_f(float s) { return s / (1.f + __expf(-s)); }
__device__ __forceinline__ float softplus_f(float x) { return (x > 20.f) ? x : log1pf(__expf(x)); }

// ---------------------------------------------------------------------------
// IN: in-proj GEMM + conv4 + silu -> xc ; silu(z) -> sz.
// grid (144, 4): 16-row tiles; yb 0/1 = x col-groups (Wi cols 0..255),
// yb 2/3 = z col-groups (Wi cols 256..511). Block 512 = 32 col-quads (tx)
// x 16 rows (ty). Per k: ONE float4 Wi load + ONE LDS broadcast scalar
// -> 4 FMA, unroll 8, <=128 VGPR (launch_bounds(512,2)) for deep load
// pipelining. A staged transposed As[k][a] (a=0..18 ~ l0-3+a). Conv via
// xis[19][132] LDS round-trip (no halo redundancy in main loop; halo rows
// computed once by ty<3). Accumulation k-ascending; conv order == round-0.
template<bool FIRST>
__global__ __launch_bounds__(512, 2)
void k_in(const float* __restrict__ seq, const float* __restrict__ x0,
          const float* __restrict__ Wi,
          const float* __restrict__ cw, const float* __restrict__ cbias,
          float* __restrict__ xc_g, float* __restrict__ sz_g) {
    __shared__ float As[128 * 20];      // As[k][a]
    __shared__ float xis[19 * 132];     // conv staging (x-blocks only)
    const int tid = threadIdx.x;
    const int l0 = blockIdx.x * 16;
    const int yb = blockIdx.y;          // 0,1 = x ; 2,3 = z
    const bool isX = (yb < 2);
    const int tx = tid & 31;
    const int ty = tid >> 5;            // 0..15 -> output row l0+ty
    const int wcol = (isX ? yb * 128 : 256 + (yb - 2) * 128) + tx * 4;

    // ---- stage A^T into LDS ----
    if (FIRST) {
        // x0 is [C][L]: consecutive threads read consecutive l (coalesced)
        for (int idx = tid; idx < 128 * 19; idx += 512) {
            const int cc = idx / 19, a = idx - cc * 19;
            const int l = l0 - 3 + a;
            As[cc * 20 + a] = (l >= 0) ? x0[cc * LSEQ + l] : 0.f;
        }
    } else {
        // seq is [L][C]: consecutive threads read consecutive col-quads
        for (int idx = tid; idx < 19 * 32; idx += 512) {
            const int a = idx >> 5, cq = idx & 31;
            const int l = l0 - 3 + a;
            float4 v = make_float4(0.f, 0.f, 0.f, 0.f);
            if (l >= 0) v = *(const float4*)&seq[l * DM + cq * 4];
            As[(cq * 4 + 0) * 20 + a] = v.x;
            As[(cq * 4 + 1) * 20 + a] = v.y;
            As[(cq * 4 + 2) * 20 + a] = v.z;
            As[(cq * 4 + 3) * 20 + a] = v.w;
        }
    }
    __syncthreads();

    // ---- main GEMM: row l0+ty, cols wcol..wcol+3 ----
    float acc[4] = {0.f, 0.f, 0.f, 0.f};
#pragma unroll 8
    for (int k = 0; k < 128; ++k) {
        const float4 b4 = *(const float4*)&Wi[k * 512 + wcol];
        const float av = As[k * 20 + 3 + ty];
        acc[0] += av * b4.x; acc[1] += av * b4.y;
        acc[2] += av * b4.z; acc[3] += av * b4.w;
    }

    if (!isX) {
        const int zc = (yb - 2) * 128 + tx * 4;
        float4 o;
        o.x = silu_f(acc[0]); o.y = silu_f(acc[1]);
        o.z = silu_f(acc[2]); o.w = silu_f(acc[3]);
        *(float4*)&sz_g[(l0 + ty) * DI + zc] = o;
        return;
    }

    // ---- halo rows l0-3..l0-1 (ty<3), Wi re-read is L1-hot ----
    float hacc[4] = {0.f, 0.f, 0.f, 0.f};
    if (ty < 3) {
#pragma unroll 8
        for (int k = 0; k < 128; ++k) {
            const float4 b4 = *(const float4*)&Wi[k * 512 + wcol];
            const float ah = As[k * 20 + ty];
            hacc[0] += ah * b4.x; hacc[1] += ah * b4.y;
            hacc[2] += ah * b4.z; hacc[3] += ah * b4.w;
        }
    }

    // ---- xi tile -> LDS, conv4 + silu, store ----
    *(float4*)&xis[(ty + 3) * 132 + tx * 4] =
        make_float4(acc[0], acc[1], acc[2], acc[3]);
    if (ty < 3)
        *(float4*)&xis[ty * 132 + tx * 4] =
            make_float4(hacc[0], hacc[1], hacc[2], hacc[3]);
    __syncthreads();

    const float4 cw0 = *(const float4*)&cw[(wcol + 0) * 4];
    const float4 cw1 = *(const float4*)&cw[(wcol + 1) * 4];
    const float4 cw2 = *(const float4*)&cw[(wcol + 2) * 4];
    const float4 cw3 = *(const float4*)&cw[(wcol + 3) * 4];
    const float4 cb4 = *(const float4*)&cbias[wcol];
    const float4 xm3 = *(const float4*)&xis[(ty + 0) * 132 + tx * 4];
    const float4 xm2 = *(const float4*)&xis[(ty + 1) * 132 + tx * 4];
    const float4 xm1 = *(const float4*)&xis[(ty + 2) * 132 + tx * 4];
    const float4 xcu = *(const float4*)&xis[(ty + 3) * 132 + tx * 4];
    float4 o;
    o.x = silu_f(cb4.x + cw0.x * xm3.x + cw0.y * xm2.x +
                 cw0.z * xm1.x + cw0.w * xcu.x);
    o.y = silu_f(cb4.y + cw1.x * xm3.y + cw1.y * xm2.y +
                 cw1.z * xm1.y + cw1.w * xcu.y);
    o.z = silu_f(cb4.z + cw2.x * xm3.z + cw2.y * xm2.z +
                 cw2.z * xm1.z + cw2.w * xcu.z);
    o.w = silu_f(cb4.w + cw3.x * xm3.w + cw3.y * xm2.w +
                 cw3.z * xm1.w + cw3.w * xcu.w);
    *(float4*)&xc_g[(l0 + ty) * DI + wcol] = o;
}

// ---------------------------------------------------------------------------
// MID: xc @ Wx -> (dtr, B, C) ; dt = softplus(dtr@Wdt+bdt) ; chunk scan -> P,S.
// grid 576; block 512: thread tid owns states [tid*8, tid*8+8) of the chunk
// (d = tid>>1, state-half = tid&1). P/S stores fully coalesced.  (r10 proven)
__global__ __launch_bounds__(512, 4)
void k_mid2(const float* __restrict__ xc_g,
            const float* __restrict__ Wx,
            const float* __restrict__ Wdt, const float* __restrict__ bdt,
            const float* __restrict__ Alog,
            float* __restrict__ dbl_g, float* __restrict__ dt_g,
            float* __restrict__ P, float* __restrict__ S) {
    __shared__ float xcs[CLEN * 256];
    __shared__ float part[4 * 160];
    __shared__ float dtrs[CLEN * 8];
    __shared__ float dbls[CLEN * 32];
    const int c = blockIdx.x;
    const int l0 = c * CLEN;
    const int tid = threadIdx.x;
    const int d = tid >> 1;
    const int sh = tid & 1;

    if (tid < 256) ((float4*)xcs)[tid] = ((const float4*)&xc_g[l0 * DI])[tid];
    __syncthreads();

    for (int task = tid; task < 640; task += 512) {
        const int kc = task / 160;
        const int o = task - kc * 160;
        const int r = o / 40, j = o - r * 40;
        const float* xr = &xcs[r * 256 + kc * 64];
        const float* wp = &Wx[(kc * 64) * 40 + j];
        float acc = 0.f;
#pragma unroll 8
        for (int k = 0; k < 64; ++k) acc += xr[k] * wp[k * 40];
        part[kc * 160 + o] = acc;
    }
    __syncthreads();
    if (tid < 160) {
        const float acc = part[tid] + part[160 + tid] + part[320 + tid] + part[480 + tid];
        const int r = tid / 40, j = tid - r * 40;
        if (j < RK) dtrs[r * 8 + j] = acc;
        else {
            dbls[r * 32 + (j - 8)] = acc;
            dbl_g[(l0 + r) * 32 + (j - 8)] = acc;
        }
    }
    __syncthreads();

    float dtv[CLEN], xcv[CLEN];
    {
        float wdt[8];
#pragma unroll
        for (int q = 0; q < 8; ++q) wdt[q] = Wdt[q * DI + d];
        const float bdv = bdt[d];
#pragma unroll
        for (int r = 0; r < CLEN; ++r) {
            float acc = bdv;
#pragma unroll
            for (int q = 0; q < 8; ++q) acc += dtrs[r * 8 + q] * wdt[q];
            dtv[r] = softplus_f(acc);
            if (sh == 0) dt_g[(l0 + r) * DI + d] = dtv[r];
            xcv[r] = xcs[r * 256 + d];
        }
    }

    float A[8], pr[8], hs[8];
#pragma unroll
    for (int v = 0; v < 2; ++v) {
        const float4 a4 = *(const float4*)&Alog[tid * 8 + v * 4];
        A[v * 4 + 0] = -__expf(a4.x);
        A[v * 4 + 1] = -__expf(a4.y);
        A[v * 4 + 2] = -__expf(a4.z);
        A[v * 4 + 3] = -__expf(a4.w);
    }
#pragma unroll
    for (int s = 0; s < 8; ++s) { pr[s] = 1.f; hs[s] = 0.f; }
#pragma unroll
    for (int t = 0; t < CLEN; ++t) {
        const float dtt = dtv[t];
        const float uv = dtt * xcv[t];
        const float* Brow = &dbls[t * 32 + sh * 8];
#pragma unroll
        for (int s = 0; s < 8; ++s) {
            const float e = __expf(dtt * A[s]);
            pr[s] *= e;
            hs[s] = e * hs[s] + uv * Brow[s];
        }
    }
    const int base = c * NSI + tid * 8;
#pragma unroll
    for (int v = 0; v < 2; ++v) {
        *(float4*)&P[base + v * 4] =
            make_float4(pr[v * 4], pr[v * 4 + 1], pr[v * 4 + 2], pr[v * 4 + 3]);
        *(float4*)&S[base + v * 4] =
            make_float4(hs[v * 4], hs[v * 4 + 1], hs[v * 4 + 2], hs[v * 4 + 3]);
    }
}

// ---------------------------------------------------------------------------
// CARRY1: per group of GS chunks, in place. grid (NG, 16); block 256.
__global__ __launch_bounds__(256, 4)
void k_carry1(float* __restrict__ P, float* __restrict__ S,
              float* __restrict__ Pg, float* __restrict__ Sg) {
    const int g = blockIdx.x;
    const int i = blockIdx.y * 256 + threadIdx.x;
    float G = 0.f, Pp = 1.f;
    const int base = g * GS * NSI + i;
#pragma unroll 8
    for (int k = 0; k < GS; ++k) {
        const int idx = base + k * NSI;
        const float p = P[idx];
        const float s = S[idx];
        S[idx] = G;
        P[idx] = Pp;
        G = p * G + s;
        Pp *= p;
    }
    Pg[g * NSI + i] = Pp;
    Sg[g * NSI + i] = G;
}

// ---------------------------------------------------------------------------
// CARRY2: serial over NG groups. grid 16 x 256.
__global__ __launch_bounds__(256, 4)
void k_carry2(const float* __restrict__ Pg, float* __restrict__ Sg) {
    const int i = blockIdx.x * 256 + threadIdx.x;
    float G = 0.f;
#pragma unroll 8
    for (int g = 0; g < NG; ++g) {
        const int idx = g * NSI + i;
        const float p = Pg[idx];
        const float s = Sg[idx];
        Sg[idx] = G;
        G = p * G + s;
    }
}

// ---------------------------------------------------------------------------
// TAIL: h0 = Sloc + Pprefix * Ggroup ; re-scan + gate + out-GEMM + rmsnorm.
// grid 576; block 512 (r10 proven).
template<bool LAST>
__global__ __launch_bounds__(512, 4)
void k_tail(const float* __restrict__ dt_g, const float* __restrict__ xc_g,
            const float* __restrict__ dbl_g, const float* __restrict__ Alog,
            const float* __restrict__ Sloc, const float* __restrict__ Ppre,
            const float* __restrict__ Gc, const float* __restrict__ Dp,
            const float* __restrict__ sz_g, const float* __restrict__ Wo,
            const float* __restrict__ rmsw, float* __restrict__ seq,
            float* __restrict__ out) {
    __shared__ float dbls[CLEN * 32];
    __shared__ float Ys[CLEN * 256];
    __shared__ float partO[8 * CLEN * 128];
    __shared__ float Os[CLEN * 129];
    __shared__ float red[CLEN * 32];
    __shared__ float scaleS[CLEN];
    const int c = blockIdx.x;
    const int g = c / GS;
    const int l0 = c * CLEN;
    const int tid = threadIdx.x;
    const int d = tid >> 1;
    const int sh = tid & 1;

    if (tid < CLEN * 32) dbls[tid] = dbl_g[l0 * 32 + tid];

    float A[8], h[8];
#pragma unroll
    for (int v = 0; v < 2; ++v) {
        const float4 a4 = *(const float4*)&Alog[tid * 8 + v * 4];
        A[v * 4 + 0] = -__expf(a4.x);
        A[v * 4 + 1] = -__expf(a4.y);
        A[v * 4 + 2] = -__expf(a4.z);
        A[v * 4 + 3] = -__expf(a4.w);
        const float4 s4 = *(const float4*)&Sloc[c * NSI + tid * 8 + v * 4];
        const float4 p4 = *(const float4*)&Ppre[c * NSI + tid * 8 + v * 4];
        const float4 g4 = *(const float4*)&Gc[g * NSI + tid * 8 + v * 4];
        h[v * 4 + 0] = s4.x + p4.x * g4.x;
        h[v * 4 + 1] = s4.y + p4.y * g4.y;
        h[v * 4 + 2] = s4.z + p4.z * g4.z;
        h[v * 4 + 3] = s4.w + p4.w * g4.w;
    }
    float dtv[CLEN], xcv[CLEN], szv[CLEN];
#pragma unroll
    for (int r = 0; r < CLEN; ++r) {
        dtv[r] = dt_g[(l0 + r) * DI + d];
        xcv[r] = xc_g[(l0 + r) * DI + d];
        szv[r] = sz_g[(l0 + r) * DI + d];
    }
    const float dskip = Dp[d];
    __syncthreads();
#pragma unroll
    for (int t = 0; t < CLEN; ++t) {
        const float dtt = dtv[t];
        const float uv = dtt * xcv[t];
        const float* Brow = &dbls[t * 32 + sh * 8];
        const float* Crow = &dbls[t * 32 + 16 + sh * 8];
        float ps = 0.f;
#pragma unroll
        for (int s = 0; s < 8; ++s) {
            const float e = __expf(dtt * A[s]);
            h[s] = e * h[s] + uv * Brow[s];
            ps += h[s] * Crow[s];
        }
        ps += __shfl_xor(ps, 1);
        if (sh == 0) Ys[t * 256 + d] = (ps + dskip * xcv[t]) * szv[t];
    }
    __syncthreads();

    {
        const int ccp = tid & 63;
        const int kg = tid >> 6;          // 0..7
        float acc[CLEN][2];
#pragma unroll
        for (int r = 0; r < CLEN; ++r) { acc[r][0] = 0.f; acc[r][1] = 0.f; }
        const float* wp = &Wo[(kg * 32) * DM + ccp * 2];
        const float* yp = &Ys[kg * 32];
#pragma unroll 4
        for (int k4 = 0; k4 < 8; ++k4) {
            const float2 w0 = *(const float2*)(wp + (k4 * 4 + 0) * DM);
            const float2 w1 = *(const float2*)(wp + (k4 * 4 + 1) * DM);
            const float2 w2 = *(const float2*)(wp + (k4 * 4 + 2) * DM);
            const float2 w3 = *(const float2*)(wp + (k4 * 4 + 3) * DM);
            float4 y4[CLEN];
#pragma unroll
            for (int r = 0; r < CLEN; ++r)
                y4[r] = *(const float4*)&yp[r * 256 + k4 * 4];
#pragma unroll
            for (int r = 0; r < CLEN; ++r) {
                acc[r][0] += y4[r].x * w0.x; acc[r][1] += y4[r].x * w0.y;
            }
#pragma unroll
            for (int r = 0; r < CLEN; ++r) {
                acc[r][0] += y4[r].y * w1.x; acc[r][1] += y4[r].y * w1.y;
            }
#pragma unroll
            for (int r = 0; r < CLEN; ++r) {
                acc[r][0] += y4[r].z * w2.x; acc[r][1] += y4[r].z * w2.y;
            }
#pragma unroll
            for (int r = 0; r < CLEN; ++r) {
                acc[r][0] += y4[r].w * w3.x; acc[r][1] += y4[r].w * w3.y;
            }
        }
#pragma unroll
        for (int r = 0; r < CLEN; ++r) {
            partO[(kg * CLEN + r) * 128 + ccp * 2 + 0] = acc[r][0];
            partO[(kg * CLEN + r) * 128 + ccp * 2 + 1] = acc[r][1];
        }
        __syncthreads();
        for (int idx = tid; idx < CLEN * 128; idx += 512) {
            const int r = idx >> 7, cc = idx & 127;
            float s = 0.f;
#pragma unroll
            for (int kgi = 0; kgi < 8; ++kgi)
                s += partO[(kgi * CLEN + r) * 128 + cc];
            Os[r * 129 + cc] = s;
        }
        __syncthreads();
    }

    if (tid < CLEN * 32) {
        const int r = tid >> 5, pp = tid & 31;
        float ss = 0.f;
#pragma unroll
        for (int i = 0; i < 4; ++i) {
            const float v = Os[r * 129 + pp * 4 + i];
            ss += v * v;
        }
        red[tid] = ss;
    }
    __syncthreads();
    if (tid < CLEN) {
        float ss = 0.f;
#pragma unroll
        for (int p = 0; p < 32; ++p) ss += red[tid * 32 + p];
        scaleS[tid] = rsqrtf(ss * (1.f / DM) + EPSF);
    }
    __syncthreads();
    if (LAST) {
        for (int idx = tid; idx < CLEN * DM; idx += 512) {
            const int r = idx >> 7, cc = idx & 127;
            out[cc * LSEQ + (l0 + r)] = Os[r * 129 + cc] * scaleS[r] * rmsw[cc];
        }
    } else {
        for (int idx = tid; idx < CLEN * DM; idx += 512) {
            const int r = idx >> 7, cc = idx & 127;
            seq[(l0 + r) * DM + cc] = Os[r * 129 + cc] * scaleS[r] * rmsw[cc];
        }
    }
}

// ---------------------------------------------------------------------------
extern "C" void kernel_launch(void* const* d_in, const int* in_sizes, int n_in,
                              void* d_out, int out_size, void* d_ws, size_t ws_size,
                              hipStream_t stream) {
    const float* x    = (const float*)d_in[0];
    const float* W_in = (const float*)d_in[1];
    const float* cw   = (const float*)d_in[2];
    const float* cb   = (const float*)d_in[3];
    const float* Wx   = (const float*)d_in[4];
    const float* Wdt  = (const float*)d_in[5];
    const float* bdt  = (const float*)d_in[6];
    const float* Alog = (const float*)d_in[7];
    const float* Dp   = (const float*)d_in[8];
    const float* Wo   = (const float*)d_in[9];
    const float* rmsw = (const float*)d_in[10];
    float* out = (float*)d_out;

    float* ws   = (float*)d_ws;
    float* seq  = ws; ws += LSEQ * DM;
    float* szb  = ws; ws += LSEQ * DI;
    float* xcb  = ws; ws += LSEQ * DI;
    float* dtb  = ws; ws += LSEQ * DI;
    float* dblb = ws; ws += LSEQ * 32;
    float* Pb   = ws; ws += NCH * NSI;
    float* Sb   = ws; ws += NCH * NSI;
    float* Pgb  = ws; ws += NG * NSI;
    float* Sgb  = ws; ws += NG * NSI;

    for (int layer = 0; layer < 8; ++layer) {
        const float* Wi_l   = W_in + (size_t)layer * DM * 512;
        const float* cw_l   = cw   + (size_t)layer * DI * 4;
        const float* cb_l   = cb   + (size_t)layer * DI;
        const float* Wx_l   = Wx   + (size_t)layer * DI * 40;
        const float* Wdt_l  = Wdt  + (size_t)layer * RK * DI;
        const float* bdt_l  = bdt  + (size_t)layer * DI;
        const float* Alog_l = Alog + (size_t)layer * DI * DS;
        const float* Dp_l   = Dp   + (size_t)layer * DI;
        const float* Wo_l   = Wo   + (size_t)layer * DI * DM;
        const float* rmsw_l = rmsw + (size_t)layer * DM;

        if (layer == 0)
            k_in<true><<<dim3(144, 4), 512, 0, stream>>>(seq, x, Wi_l, cw_l, cb_l,
                                                         xcb, szb);
        else
            k_in<false><<<dim3(144, 4), 512, 0, stream>>>(seq, x, Wi_l, cw_l, cb_l,
                                                          xcb, szb);

        k_mid2<<<NCH, 512, 0, stream>>>(xcb, Wx_l, Wdt_l, bdt_l, Alog_l,
                                        dblb, dtb, Pb, Sb);

        k_carry1<<<dim3(NG, 16), 256, 0, stream>>>(Pb, Sb, Pgb, Sgb);
        k_carry2<<<16, 256, 0, stream>>>(Pgb, Sgb);

        if (layer == 7)
            k_tail<true><<<NCH, 512, 0, stream>>>(dtb, xcb, dblb, Alog_l, Sb, Pb,
                                                  Sgb, Dp_l, szb, Wo_l, rmsw_l,
                                                  seq, out);
        else
            k_tail<false><<<NCH, 512, 0, stream>>>(dtb, xcb, dblb, Alog_l, Sb, Pb,
                                                   Sgb, Dp_l, szb, Wo_l, rmsw_l,
                                                   seq, out);
    }
}

// Round 14
// 545.166 us; speedup vs baseline: 1.1813x; 1.1813x over previous
//
#include <hip/hip_runtime.h>
#include <math.h>

#define LSEQ 2304
#define DM 128
#define DI 256
#define DS 16
#define RK 8
#define NCH 576     // 4-row chunks
#define CLEN 4
#define NG 24       // carry groups
#define GS 24       // chunks per group (NG*GS == NCH)
#define NSI (DI*DS) // 4096 state indices
#define EPSF 1e-5f

__device__ __forceinline__ float silu_f(float s) { return s / (1.f + __expf(-s)); }
__device__ __forceinline__ float softplus_f(float x) { return (x > 20.f) ? x : log1pf(__expf(x)); }

// ---------------------------------------------------------------------------
// IN: in-proj GEMM + conv4 + silu -> xc ; silu(z) -> sz.
// grid (144, 4): 16-row x 128-col tiles; y=0/1 x-halves, y=2/3 z-halves.
// block 512 = 128 cols x 4 rowgroups(4 rows). Best-measured form (r10):
// LDS-broadcast A reads (wave-uniform float4), coalesced scalar Wi reads,
// 18 waves/CU. Halo rows recomputed in-register (ax[7] per 4-row group).
template<bool FIRST>
__global__ __launch_bounds__(512, 4)
void k_in(const float* __restrict__ seq, const float* __restrict__ x0,
          const float* __restrict__ Wi,
          const float* __restrict__ cw, const float* __restrict__ cbias,
          float* __restrict__ xc_g, float* __restrict__ sz_g) {
    __shared__ float As[19 * 128];   // seq rows l0-3 .. l0+15
    const int l0 = blockIdx.x * 16;
    const int half = blockIdx.y & 1;
    const bool isZ = blockIdx.y >= 2;
    const int tid = threadIdx.x;

    if (FIRST) {
        const int rlo = isZ ? 3 : 0;
        for (int idx = tid + rlo * 128; idx < 19 * 128; idx += 512) {
            const int r = idx >> 7, cc = idx & 127;
            const int l = l0 - 3 + r;
            As[idx] = (l >= 0) ? x0[cc * LSEQ + l] : 0.f;
        }
    } else if (!isZ) {
        // 19 rows x 32 float4
        for (int idx = tid; idx < 19 * 32; idx += 512) {
            const int r = idx >> 5, cq = (idx & 31) * 4;
            const int l = l0 - 3 + r;
            const float4 v = (l >= 0) ? *(const float4*)&seq[l * DM + cq]
                                      : make_float4(0.f, 0.f, 0.f, 0.f);
            *(float4*)&As[r * 128 + cq] = v;
        }
    } else {
        // z-blocks need rows 3..18 only: 16 rows x 32 float4 = 512 tasks
        for (int idx = tid; idx < 16 * 32; idx += 512) {
            const int r = 3 + (idx >> 5), cq = (idx & 31) * 4;
            *(float4*)&As[r * 128 + cq] =
                *(const float4*)&seq[(l0 - 3 + r) * DM + cq];
        }
    }
    __syncthreads();

    const int c = tid & 127;
    const int rg = tid >> 7;          // 0..3 -> out rows rg*4 .. rg*4+3
    const int d = half * 128 + c;

    if (!isZ) {
        float ax[7];
#pragma unroll
        for (int r = 0; r < 7; ++r) ax[r] = 0.f;
        for (int k4 = 0; k4 < 32; ++k4) {
            float bv[4];
#pragma unroll
            for (int u = 0; u < 4; ++u) bv[u] = Wi[(k4 * 4 + u) * 512 + d];
#pragma unroll
            for (int r = 0; r < 7; ++r) {
                const float4 a4 = *(const float4*)&As[(rg * 4 + r) * 128 + k4 * 4];
                ax[r] += a4.x * bv[0] + a4.y * bv[1] + a4.z * bv[2] + a4.w * bv[3];
            }
        }
        const float w0 = cw[d * 4 + 0], w1 = cw[d * 4 + 1];
        const float w2 = cw[d * 4 + 2], w3 = cw[d * 4 + 3];
        const float cbv = cbias[d];
#pragma unroll
        for (int rr = 0; rr < 4; ++rr) {
            const float v = silu_f(cbv + w0 * ax[rr] + w1 * ax[rr + 1] +
                                   w2 * ax[rr + 2] + w3 * ax[rr + 3]);
            xc_g[(l0 + rg * 4 + rr) * DI + d] = v;
        }
    } else {
        float az[4];
#pragma unroll
        for (int r = 0; r < 4; ++r) az[r] = 0.f;
        for (int k4 = 0; k4 < 32; ++k4) {
            float bv[4];
#pragma unroll
            for (int u = 0; u < 4; ++u) bv[u] = Wi[(k4 * 4 + u) * 512 + 256 + d];
#pragma unroll
            for (int r = 0; r < 4; ++r) {
                const float4 a4 = *(const float4*)&As[(rg * 4 + r + 3) * 128 + k4 * 4];
                az[r] += a4.x * bv[0] + a4.y * bv[1] + a4.z * bv[2] + a4.w * bv[3];
            }
        }
#pragma unroll
        for (int rr = 0; rr < 4; ++rr)
            sz_g[(l0 + rg * 4 + rr) * DI + d] = silu_f(az[rr]);
    }
}

// ---------------------------------------------------------------------------
// MID: xc @ Wx -> (dtr, B, C) ; dt = softplus(dtr@Wdt+bdt) ; chunk scan -> P,S.
// grid 576; block 512: thread tid owns states [tid*8, tid*8+8) of the chunk
// (d = tid>>1, state-half = tid&1). P/S stores fully coalesced.
__global__ __launch_bounds__(512, 4)
void k_mid2(const float* __restrict__ xc_g,
            const float* __restrict__ Wx,
            const float* __restrict__ Wdt, const float* __restrict__ bdt,
            const float* __restrict__ Alog,
            float* __restrict__ dbl_g, float* __restrict__ dt_g,
            float* __restrict__ P, float* __restrict__ S) {
    __shared__ float xcs[CLEN * 256];
    __shared__ float part[4 * 160];
    __shared__ float dtrs[CLEN * 8];
    __shared__ float dbls[CLEN * 32];
    const int c = blockIdx.x;
    const int l0 = c * CLEN;
    const int tid = threadIdx.x;
    const int d = tid >> 1;
    const int sh = tid & 1;

    // stage 4 xc rows: 256 float4, fully coalesced
    if (tid < 256) ((float4*)xcs)[tid] = ((const float4*)&xc_g[l0 * DI])[tid];
    __syncthreads();

    // xproj: 160 outputs x 4 K-quarters = 640 tasks over 512 threads
    for (int task = tid; task < 640; task += 512) {
        const int kc = task / 160;
        const int o = task - kc * 160;
        const int r = o / 40, j = o - r * 40;
        const float* xr = &xcs[r * 256 + kc * 64];
        const float* wp = &Wx[(kc * 64) * 40 + j];
        float acc = 0.f;
#pragma unroll 8
        for (int k = 0; k < 64; ++k) acc += xr[k] * wp[k * 40];
        part[kc * 160 + o] = acc;
    }
    __syncthreads();
    if (tid < 160) {
        const float acc = part[tid] + part[160 + tid] + part[320 + tid] + part[480 + tid];
        const int r = tid / 40, j = tid - r * 40;
        if (j < RK) dtrs[r * 8 + j] = acc;
        else {
            dbls[r * 32 + (j - 8)] = acc;
            dbl_g[(l0 + r) * 32 + (j - 8)] = acc;
        }
    }
    __syncthreads();

    // dt = softplus(dtr @ Wdt + bdt) per d (pair-duplicated)
    float dtv[CLEN], xcv[CLEN];
    {
        float wdt[8];
#pragma unroll
        for (int q = 0; q < 8; ++q) wdt[q] = Wdt[q * DI + d];
        const float bdv = bdt[d];
#pragma unroll
        for (int r = 0; r < CLEN; ++r) {
            float acc = bdv;
#pragma unroll
            for (int q = 0; q < 8; ++q) acc += dtrs[r * 8 + q] * wdt[q];
            dtv[r] = softplus_f(acc);
            if (sh == 0) dt_g[(l0 + r) * DI + d] = dtv[r];
            xcv[r] = xcs[r * 256 + d];
        }
    }

    // chunk-local scan: 8 states per thread (global state idx i0 = tid*8)
    float A[8], pr[8], hs[8];
#pragma unroll
    for (int v = 0; v < 2; ++v) {
        const float4 a4 = *(const float4*)&Alog[tid * 8 + v * 4];
        A[v * 4 + 0] = -__expf(a4.x);
        A[v * 4 + 1] = -__expf(a4.y);
        A[v * 4 + 2] = -__expf(a4.z);
        A[v * 4 + 3] = -__expf(a4.w);
    }
#pragma unroll
    for (int s = 0; s < 8; ++s) { pr[s] = 1.f; hs[s] = 0.f; }
#pragma unroll
    for (int t = 0; t < CLEN; ++t) {
        const float dtt = dtv[t];
        const float uv = dtt * xcv[t];
        const float* Brow = &dbls[t * 32 + sh * 8];
#pragma unroll
        for (int s = 0; s < 8; ++s) {
            const float e = __expf(dtt * A[s]);
            pr[s] *= e;
            hs[s] = e * hs[s] + uv * Brow[s];
        }
    }
    const int base = c * NSI + tid * 8;
#pragma unroll
    for (int v = 0; v < 2; ++v) {
        *(float4*)&P[base + v * 4] =
            make_float4(pr[v * 4], pr[v * 4 + 1], pr[v * 4 + 2], pr[v * 4 + 3]);
        *(float4*)&S[base + v * 4] =
            make_float4(hs[v * 4], hs[v * 4 + 1], hs[v * 4 + 2], hs[v * 4 + 3]);
    }
}

// ---------------------------------------------------------------------------
// CARRY1: per group of GS chunks, in place: P -> prefix product, S -> local
// carry; emit group aggregates. grid (NG, 16); block 256.
__global__ __launch_bounds__(256, 4)
void k_carry1(float* __restrict__ P, float* __restrict__ S,
              float* __restrict__ Pg, float* __restrict__ Sg) {
    const int g = blockIdx.x;
    const int i = blockIdx.y * 256 + threadIdx.x;
    float G = 0.f, Pp = 1.f;
    const int base = g * GS * NSI + i;
#pragma unroll 8
    for (int k = 0; k < GS; ++k) {
        const int idx = base + k * NSI;
        const float p = P[idx];
        const float s = S[idx];
        S[idx] = G;
        P[idx] = Pp;
        G = p * G + s;
        Pp *= p;
    }
    Pg[g * NSI + i] = Pp;
    Sg[g * NSI + i] = G;
}

// ---------------------------------------------------------------------------
// CARRY2: serial over NG groups: Sg[g] <- carry INTO group g. grid 16 x 256.
__global__ __launch_bounds__(256, 4)
void k_carry2(const float* __restrict__ Pg, float* __restrict__ Sg) {
    const int i = blockIdx.x * 256 + threadIdx.x;
    float G = 0.f;
#pragma unroll 8
    for (int g = 0; g < NG; ++g) {
        const int idx = g * NSI + i;
        const float p = Pg[idx];
        const float s = Sg[idx];
        Sg[idx] = G;
        G = p * G + s;
    }
}

// ---------------------------------------------------------------------------
// TAIL: h0 = Sloc + Pprefix * Ggroup ; re-scan + gate + out-GEMM + rmsnorm.
// grid 576; block 512: thread tid owns states [tid*8, tid*8+8); per-t
// C-projection partial combined across the (even,odd) lane pair via
// __shfl_xor. Out-GEMM: 64 cc-pairs x 8 K-groups (K=32 each).
template<bool LAST>
__global__ __launch_bounds__(512, 4)
void k_tail(const float* __restrict__ dt_g, const float* __restrict__ xc_g,
            const float* __restrict__ dbl_g, const float* __restrict__ Alog,
            const float* __restrict__ Sloc, const float* __restrict__ Ppre,
            const float* __restrict__ Gc, const float* __restrict__ Dp,
            const float* __restrict__ sz_g, const float* __restrict__ Wo,
            const float* __restrict__ rmsw, float* __restrict__ seq,
            float* __restrict__ out) {
    __shared__ float dbls[CLEN * 32];         // 128
    __shared__ float Ys[CLEN * 256];          // 1024
    __shared__ float partO[8 * CLEN * 128];   // [kg][r][cc] 4096
    __shared__ float Os[CLEN * 129];
    __shared__ float red[CLEN * 32];
    __shared__ float scaleS[CLEN];
    const int c = blockIdx.x;
    const int g = c / GS;
    const int l0 = c * CLEN;
    const int tid = threadIdx.x;
    const int d = tid >> 1;
    const int sh = tid & 1;

    if (tid < CLEN * 32) dbls[tid] = dbl_g[l0 * 32 + tid];

    float A[8], h[8];
#pragma unroll
    for (int v = 0; v < 2; ++v) {
        const float4 a4 = *(const float4*)&Alog[tid * 8 + v * 4];
        A[v * 4 + 0] = -__expf(a4.x);
        A[v * 4 + 1] = -__expf(a4.y);
        A[v * 4 + 2] = -__expf(a4.z);
        A[v * 4 + 3] = -__expf(a4.w);
        const float4 s4 = *(const float4*)&Sloc[c * NSI + tid * 8 + v * 4];
        const float4 p4 = *(const float4*)&Ppre[c * NSI + tid * 8 + v * 4];
        const float4 g4 = *(const float4*)&Gc[g * NSI + tid * 8 + v * 4];
        h[v * 4 + 0] = s4.x + p4.x * g4.x;
        h[v * 4 + 1] = s4.y + p4.y * g4.y;
        h[v * 4 + 2] = s4.z + p4.z * g4.z;
        h[v * 4 + 3] = s4.w + p4.w * g4.w;
    }
    float dtv[CLEN], xcv[CLEN], szv[CLEN];
#pragma unroll
    for (int r = 0; r < CLEN; ++r) {
        dtv[r] = dt_g[(l0 + r) * DI + d];
        xcv[r] = xc_g[(l0 + r) * DI + d];
        szv[r] = sz_g[(l0 + r) * DI + d];
    }
    const float dskip = Dp[d];
    __syncthreads();
#pragma unroll
    for (int t = 0; t < CLEN; ++t) {
        const float dtt = dtv[t];
        const float uv = dtt * xcv[t];
        const float* Brow = &dbls[t * 32 + sh * 8];
        const float* Crow = &dbls[t * 32 + 16 + sh * 8];
        float ps = 0.f;
#pragma unroll
        for (int s = 0; s < 8; ++s) {
            const float e = __expf(dtt * A[s]);
            h[s] = e * h[s] + uv * Brow[s];
            ps += h[s] * Crow[s];
        }
        ps += __shfl_xor(ps, 1);
        if (sh == 0) Ys[t * 256 + d] = (ps + dskip * xcv[t]) * szv[t];
    }
    __syncthreads();

    // out-GEMM: 64 cc-pairs x 8 K-groups (K=32 each); float2 Wo, float4 Ys
    {
        const int ccp = tid & 63;
        const int kg = tid >> 6;          // 0..7
        float acc[CLEN][2];
#pragma unroll
        for (int r = 0; r < CLEN; ++r) { acc[r][0] = 0.f; acc[r][1] = 0.f; }
        const float* wp = &Wo[(kg * 32) * DM + ccp * 2];
        const float* yp = &Ys[kg * 32];
#pragma unroll 4
        for (int k4 = 0; k4 < 8; ++k4) {
            const float2 w0 = *(const float2*)(wp + (k4 * 4 + 0) * DM);
            const float2 w1 = *(const float2*)(wp + (k4 * 4 + 1) * DM);
            const float2 w2 = *(const float2*)(wp + (k4 * 4 + 2) * DM);
            const float2 w3 = *(const float2*)(wp + (k4 * 4 + 3) * DM);
            float4 y4[CLEN];
#pragma unroll
            for (int r = 0; r < CLEN; ++r)
                y4[r] = *(const float4*)&yp[r * 256 + k4 * 4];
#pragma unroll
            for (int r = 0; r < CLEN; ++r) {
                acc[r][0] += y4[r].x * w0.x; acc[r][1] += y4[r].x * w0.y;
            }
#pragma unroll
            for (int r = 0; r < CLEN; ++r) {
                acc[r][0] += y4[r].y * w1.x; acc[r][1] += y4[r].y * w1.y;
            }
#pragma unroll
            for (int r = 0; r < CLEN; ++r) {
                acc[r][0] += y4[r].z * w2.x; acc[r][1] += y4[r].z * w2.y;
            }
#pragma unroll
            for (int r = 0; r < CLEN; ++r) {
                acc[r][0] += y4[r].w * w3.x; acc[r][1] += y4[r].w * w3.y;
            }
        }
#pragma unroll
        for (int r = 0; r < CLEN; ++r) {
            partO[(kg * CLEN + r) * 128 + ccp * 2 + 0] = acc[r][0];
            partO[(kg * CLEN + r) * 128 + ccp * 2 + 1] = acc[r][1];
        }
        __syncthreads();
        for (int idx = tid; idx < CLEN * 128; idx += 512) {
            const int r = idx >> 7, cc = idx & 127;
            float s = 0.f;
#pragma unroll
            for (int kgi = 0; kgi < 8; ++kgi)
                s += partO[(kgi * CLEN + r) * 128 + cc];
            Os[r * 129 + cc] = s;
        }
        __syncthreads();
    }

    // rmsnorm + store
    if (tid < CLEN * 32) {
        const int r = tid >> 5, pp = tid & 31;
        float ss = 0.f;
#pragma unroll
        for (int i = 0; i < 4; ++i) {
            const float v = Os[r * 129 + pp * 4 + i];
            ss += v * v;
        }
        red[tid] = ss;
    }
    __syncthreads();
    if (tid < CLEN) {
        float ss = 0.f;
#pragma unroll
        for (int p = 0; p < 32; ++p) ss += red[tid * 32 + p];
        scaleS[tid] = rsqrtf(ss * (1.f / DM) + EPSF);
    }
    __syncthreads();
    if (LAST) {
        for (int idx = tid; idx < CLEN * DM; idx += 512) {
            const int r = idx >> 7, cc = idx & 127;
            out[cc * LSEQ + (l0 + r)] = Os[r * 129 + cc] * scaleS[r] * rmsw[cc];
        }
    } else {
        for (int idx = tid; idx < CLEN * DM; idx += 512) {
            const int r = idx >> 7, cc = idx & 127;
            seq[(l0 + r) * DM + cc] = Os[r * 129 + cc] * scaleS[r] * rmsw[cc];
        }
    }
}

// ---------------------------------------------------------------------------
extern "C" void kernel_launch(void* const* d_in, const int* in_sizes, int n_in,
                              void* d_out, int out_size, void* d_ws, size_t ws_size,
                              hipStream_t stream) {
    const float* x    = (const float*)d_in[0];
    const float* W_in = (const float*)d_in[1];
    const float* cw   = (const float*)d_in[2];
    const float* cb   = (const float*)d_in[3];
    const float* Wx   = (const float*)d_in[4];
    const float* Wdt  = (const float*)d_in[5];
    const float* bdt  = (const float*)d_in[6];
    const float* Alog = (const float*)d_in[7];
    const float* Dp   = (const float*)d_in[8];
    const float* Wo   = (const float*)d_in[9];
    const float* rmsw = (const float*)d_in[10];
    float* out = (float*)d_out;

    float* ws   = (float*)d_ws;
    float* seq  = ws; ws += LSEQ * DM;
    float* szb  = ws; ws += LSEQ * DI;
    float* xcb  = ws; ws += LSEQ * DI;
    float* dtb  = ws; ws += LSEQ * DI;
    float* dblb = ws; ws += LSEQ * 32;
    float* Pb   = ws; ws += NCH * NSI;
    float* Sb   = ws; ws += NCH * NSI;
    float* Pgb  = ws; ws += NG * NSI;
    float* Sgb  = ws; ws += NG * NSI;

    for (int layer = 0; layer < 8; ++layer) {
        const float* Wi_l   = W_in + (size_t)layer * DM * 512;
        const float* cw_l   = cw   + (size_t)layer * DI * 4;
        const float* cb_l   = cb   + (size_t)layer * DI;
        const float* Wx_l   = Wx   + (size_t)layer * DI * 40;
        const float* Wdt_l  = Wdt  + (size_t)layer * RK * DI;
        const float* bdt_l  = bdt  + (size_t)layer * DI;
        const float* Alog_l = Alog + (size_t)layer * DI * DS;
        const float* Dp_l   = Dp   + (size_t)layer * DI;
        const float* Wo_l   = Wo   + (size_t)layer * DI * DM;
        const float* rmsw_l = rmsw + (size_t)layer * DM;

        if (layer == 0)
            k_in<true><<<dim3(144, 4), 512, 0, stream>>>(seq, x, Wi_l, cw_l, cb_l,
                                                         xcb, szb);
        else
            k_in<false><<<dim3(144, 4), 512, 0, stream>>>(seq, x, Wi_l, cw_l, cb_l,
                                                          xcb, szb);

        k_mid2<<<NCH, 512, 0, stream>>>(xcb, Wx_l, Wdt_l, bdt_l, Alog_l,
                                        dblb, dtb, Pb, Sb);

        k_carry1<<<dim3(NG, 16), 256, 0, stream>>>(Pb, Sb, Pgb, Sgb);
        k_carry2<<<16, 256, 0, stream>>>(Pgb, Sgb);

        if (layer == 7)
            k_tail<true><<<NCH, 512, 0, stream>>>(dtb, xcb, dblb, Alog_l, Sb, Pb,
                                                  Sgb, Dp_l, szb, Wo_l, rmsw_l,
                                                  seq, out);
        else
            k_tail<false><<<NCH, 512, 0, stream>>>(dtb, xcb, dblb, Alog_l, Sb, Pb,
                                                   Sgb, Dp_l, szb, Wo_l, rmsw_l,
                                                   seq, out);
    }
}